// Round 3
// baseline (1057.355 us; speedup 1.0000x reference)
//
#include <hip/hip_runtime.h>

typedef __attribute__((ext_vector_type(8))) short short8;
typedef __attribute__((ext_vector_type(4))) float f32x4;

#define DEVFN __device__ __forceinline__

constexpr float SCALE_ATTN = 0.04419417382415922f;  // 1/sqrt(512)
constexpr float NEGF = -4294967296.0f;              // -(1<<32)

DEVFN unsigned short f2bf(float f) {
  unsigned int u = __float_as_uint(f);
  u += 0x7FFFu + ((u >> 16) & 1u);   // RNE (inputs finite)
  return (unsigned short)(u >> 16);
}
DEVFN float bf2f(unsigned short h) { return __uint_as_float((unsigned)h << 16); }

DEVFN void gl_lds16(const void* g, void* l) {
  // async global->LDS, 16B/lane; LDS dest = wave-uniform base + lane*16
  __builtin_amdgcn_global_load_lds(
      (const __attribute__((address_space(1))) unsigned int*)g,
      (__attribute__((address_space(3))) unsigned int*)l, 16, 0, 0);
}

// ---------- dtype detector on Q: 1 = bf16 elements, 0 = f32 elements ----------
__global__ void k_detect_f(const unsigned int* __restrict__ q, int* __restrict__ flag) {
  int lane = threadIdx.x;
  unsigned bad = 0;
  for (int i = 0; i < 64; i++) {
    unsigned v = q[i * 64 + lane];
    unsigned h = v & 0xFFFFu;          // if bf16 data: element 2i; if f32: mantissa bits
    unsigned e = (h >> 7) & 0xFFu;     // bf16 exponent field
    if (h != 0u && (e < 96u || e > 150u)) bad = 1;
  }
  unsigned long long anyb = __ballot(bad != 0);
  if (lane == 0) *flag = (anyb == 0ULL) ? 1 : 0;  // all sane -> bf16
}

// ---------- mask element-size detector: 1, 2, or 4 bytes ----------
__global__ void k_detect_m(const unsigned int* __restrict__ m, int* __restrict__ esize) {
  int lane = threadIdx.x;
  unsigned okd = 1, okf = 1, okh = 1, okb = 1;
  for (int i = 0; i < 64; i++) {
    unsigned v = m[i * 64 + lane];
    if (v > 1u) okd = 0;                                   // int32 0/1
    if (v != 0u && v != 0x3F800000u) okf = 0;              // f32 0/1.0
    unsigned h0 = v & 0xFFFFu, h1 = v >> 16;
    if ((h0 && h0 != 0x3F80u) || (h1 && h1 != 0x3F80u)) okh = 0;  // bf16 0/1.0
    if (v & 0xFEFEFEFEu) okb = 0;                          // bytes 0/1
  }
  okd = (__ballot(okd == 0) == 0ULL); okf = (__ballot(okf == 0) == 0ULL);
  okh = (__ballot(okh == 0) == 0ULL); okb = (__ballot(okb == 0) == 0ULL);
  if (lane == 0) *esize = okd ? 4 : (okf ? 4 : (okh ? 2 : 1));
}

// ---------- convert-or-copy -> bf16 ----------
__global__ void k_cvt(const void* __restrict__ src, unsigned short* __restrict__ dst,
                      const int* __restrict__ bf16flag, int n) {
  int i = (blockIdx.x * blockDim.x + threadIdx.x) * 8;
  if (i >= n) return;
  if (*bf16flag) {
    *(uint4*)(dst + i) = *(const uint4*)((const unsigned short*)src + i);
  } else {
    const float* f = (const float*)src + i;
    float4 a = *(const float4*)f, b = *(const float4*)(f + 4);
    uint4 o;
    o.x = (unsigned)f2bf(a.x) | ((unsigned)f2bf(a.y) << 16);
    o.y = (unsigned)f2bf(a.z) | ((unsigned)f2bf(a.w) << 16);
    o.z = (unsigned)f2bf(b.x) | ((unsigned)f2bf(b.y) << 16);
    o.w = (unsigned)f2bf(b.z) | ((unsigned)f2bf(b.w) << 16);
    *(uint4*)(dst + i) = o;
  }
}

// ---------- V [8192x512] -> V^T [512x8192] bf16 ----------
__global__ void k_transpose_v(const void* __restrict__ Vsrc, const int* __restrict__ bf16flag,
                              unsigned short* __restrict__ Vt) {
  __shared__ unsigned short T[64][72];
  int t = threadIdx.x;
  int rb = blockIdx.x, cb = blockIdx.y;  // 128 row-tiles, 8 col-tiles (64x64)
  int r = t >> 3, c8 = (t & 7) * 8;
  int isbf = *bf16flag;
#pragma unroll
  for (int j = 0; j < 2; j++) {
    int row = rb * 64 + j * 32 + r;
    unsigned short e[8];
    if (isbf) {
      alignas(16) unsigned short tmp[8];
      *(uint4*)tmp = *(const uint4*)((const unsigned short*)Vsrc + (size_t)row * 512 + cb * 64 + c8);
#pragma unroll
      for (int i = 0; i < 8; i++) e[i] = tmp[i];
    } else {
      const float* f = (const float*)Vsrc + (size_t)row * 512 + cb * 64 + c8;
      float4 a = *(const float4*)f, b = *(const float4*)(f + 4);
      e[0] = f2bf(a.x); e[1] = f2bf(a.y); e[2] = f2bf(a.z); e[3] = f2bf(a.w);
      e[4] = f2bf(b.x); e[5] = f2bf(b.y); e[6] = f2bf(b.z); e[7] = f2bf(b.w);
    }
#pragma unroll
    for (int i = 0; i < 8; i++) T[c8 + i][j * 32 + r] = e[i];
  }
  __syncthreads();
#pragma unroll
  for (int j = 0; j < 2; j++) {
    int vtr = cb * 64 + j * 32 + r;
    alignas(16) unsigned short o[8];
#pragma unroll
    for (int i = 0; i < 8; i++) o[i] = T[j * 32 + r][c8 + i];
    *(uint4*)(Vt + (size_t)vtr * 8192 + rb * 64 + c8) = *(const uint4*)o;
  }
}

// ---------- mask -> bit-packed [8192][128] uint64 ----------
__global__ void k_pack(const void* __restrict__ mask, const int* __restrict__ esize,
                       unsigned long long* __restrict__ bits) {
  int gid = blockIdx.x * blockDim.x + threadIdx.x;
  int wv = gid >> 6, lane = gid & 63;
  int sz = *esize;
  for (int w = wv; w < 1048576; w += 4096) {
    size_t base = (size_t)w * 64 + lane;
    bool pred;
    if (sz == 1)      pred = ((const unsigned char*)mask)[base] != 0;
    else if (sz == 2) pred = ((const unsigned short*)mask)[base] != 0;
    else              pred = ((const unsigned int*)mask)[base] != 0u;
    unsigned long long b = __ballot(pred);
    if (lane == 0) bits[w] = b;
  }
}

// ---------- proj GEMM: out_bf16[8192x512] = A @ W^T + bias ----------
__global__ __launch_bounds__(256, 2) void k_proj(const unsigned short* __restrict__ A,
                                                 const unsigned short* __restrict__ W,
                                                 const unsigned short* __restrict__ bias,
                                                 unsigned short* __restrict__ out) {
  __shared__ alignas(16) unsigned short As[128 * 64];
  __shared__ alignas(16) unsigned short Bs[128 * 64];
  int tid = threadIdx.x, lane = tid & 63, wave = tid >> 6;
  int wi = wave >> 1, wj = wave & 1;
  int l15 = lane & 15, l4 = lane >> 4;
  int rowbase = blockIdx.x * 128, colbase = blockIdx.y * 128;
  f32x4 acc[4][4];
#pragma unroll
  for (int i = 0; i < 4; i++)
#pragma unroll
    for (int j = 0; j < 4; j++) acc[i][j] = f32x4{0.f, 0.f, 0.f, 0.f};

  for (int kb = 0; kb < 512; kb += 64) {
    __syncthreads();
#pragma unroll
    for (int t = 0; t < 4; t++) {
      int inst = wave * 4 + t;  // 16 insts, 8 rows x 64 cols each
      int r = inst * 8 + (lane >> 3), c = (lane & 7) * 8;
      gl_lds16(A + (size_t)(rowbase + r) * 512 + kb + c, &As[inst * 512]);
      gl_lds16(W + (size_t)(colbase + r) * 512 + kb + c, &Bs[inst * 512]);
    }
    __syncthreads();
#pragma unroll
    for (int t2 = 0; t2 < 2; t2++) {
      short8 a[4], b[4];
#pragma unroll
      for (int i = 0; i < 4; i++)
        a[i] = *(const short8*)&As[(wi * 64 + i * 16 + l15) * 64 + t2 * 32 + l4 * 8];
#pragma unroll
      for (int j = 0; j < 4; j++)
        b[j] = *(const short8*)&Bs[(wj * 64 + j * 16 + l15) * 64 + t2 * 32 + l4 * 8];
#pragma unroll
      for (int i = 0; i < 4; i++)
#pragma unroll
        for (int j = 0; j < 4; j++)
          acc[i][j] = __builtin_amdgcn_mfma_f32_16x16x32_bf16(a[i], b[j], acc[i][j], 0, 0, 0);
    }
  }
#pragma unroll
  for (int j = 0; j < 4; j++) {
    int col = colbase + wj * 64 + j * 16 + l15;
    float bj = bf2f(bias[col]);
#pragma unroll
    for (int i = 0; i < 4; i++) {
      int row0 = rowbase + wi * 64 + i * 16 + l4 * 4;
#pragma unroll
      for (int r = 0; r < 4; r++)
        out[(size_t)(row0 + r) * 512 + col] = f2bf(acc[i][j][r] + bj);
    }
  }
}

// ---------- flash attention, split-K=4, BM=128, BN=64 ----------
__global__ __launch_bounds__(512, 2) void k_attn(
    const unsigned short* __restrict__ Qp, const unsigned short* __restrict__ Kp,
    const unsigned short* __restrict__ Vt, const unsigned long long* __restrict__ mbits,
    float* __restrict__ Opart, float* __restrict__ mpart, float* __restrict__ lpart) {
  __shared__ alignas(16) unsigned short SH[16384];   // 32KB staging
  __shared__ alignas(16) unsigned short P[128 * 64]; // 16KB wave-private
  int tid = threadIdx.x, lane = tid & 63, wave = tid >> 6;
  int l15 = lane & 15, l4 = lane >> 4;
  int qb = blockIdx.x * 128;
  int split = blockIdx.y;

  short8 qf[16];  // persistent Q fragments (64 VGPRs)
  {
    int row = qb + wave * 16 + l15;
#pragma unroll
    for (int t = 0; t < 16; t++)
      qf[t] = *(const short8*)(Qp + (size_t)row * 512 + t * 32 + l4 * 8);
  }
  f32x4 o[32];
#pragma unroll
  for (int f = 0; f < 32; f++) o[f] = f32x4{0.f, 0.f, 0.f, 0.f};
  float mi[4] = {NEGF, NEGF, NEGF, NEGF};
  float li[4] = {0.f, 0.f, 0.f, 0.f};

  for (int it = 0; it < 32; it++) {
    int kb = split * 2048 + it * 64;
    unsigned long long mw[4];
#pragma unroll
    for (int r = 0; r < 4; r++)
      mw[r] = mbits[(size_t)(qb + wave * 16 + l4 * 4 + r) * 128 + (kb >> 6)];

    f32x4 sacc[4];
#pragma unroll
    for (int c = 0; c < 4; c++) sacc[c] = f32x4{0.f, 0.f, 0.f, 0.f};

#pragma unroll
    for (int dc = 0; dc < 2; dc++) {
      __syncthreads();
#pragma unroll
      for (int t = 0; t < 4; t++) {
        int inst = wave * 4 + t;  // 32 insts, 2 K-rows x 256 cols
        gl_lds16(Kp + (size_t)(kb + inst * 2 + (lane >> 5)) * 512 + dc * 256 + (lane & 31) * 8,
                 &SH[inst * 512]);
      }
      __syncthreads();
#pragma unroll
      for (int t2 = 0; t2 < 8; t2++) {
        short8 a = qf[dc * 8 + t2];
#pragma unroll
        for (int c = 0; c < 4; c++) {
          short8 b = *(const short8*)&SH[(c * 16 + l15) * 256 + t2 * 32 + l4 * 8];
          sacc[c] = __builtin_amdgcn_mfma_f32_16x16x32_bf16(a, b, sacc[c], 0, 0, 0);
        }
      }
    }

#pragma unroll
    for (int c = 0; c < 4; c++)
#pragma unroll
      for (int r = 0; r < 4; r++) {
        float s = sacc[c][r] * SCALE_ATTN;
        bool msk = (mw[r] >> (c * 16 + l15)) & 1ULL;
        sacc[c][r] = msk ? NEGF : s;
      }

    float alpha[4], mnew[4];
#pragma unroll
    for (int r = 0; r < 4; r++) {
      float t = fmaxf(fmaxf(sacc[0][r], sacc[1][r]), fmaxf(sacc[2][r], sacc[3][r]));
#pragma unroll
      for (int off = 1; off < 16; off <<= 1) t = fmaxf(t, __shfl_xor(t, off, 64));
      float mn = fmaxf(mi[r], t);
      alpha[r] = __expf(mi[r] - mn);
      mi[r] = mn; mnew[r] = mn;
    }
#pragma unroll
    for (int c = 0; c < 4; c++)
#pragma unroll
      for (int r = 0; r < 4; r++)
        sacc[c][r] = __expf(sacc[c][r] - mnew[r]);
#pragma unroll
    for (int r = 0; r < 4; r++) {
      float t = sacc[0][r] + sacc[1][r] + sacc[2][r] + sacc[3][r];
#pragma unroll
      for (int off = 1; off < 16; off <<= 1) t += __shfl_xor(t, off, 64);
      li[r] = li[r] * alpha[r] + t;
    }
#pragma unroll
    for (int f = 0; f < 32; f++)
#pragma unroll
      for (int r = 0; r < 4; r++) o[f][r] *= alpha[r];

#pragma unroll
    for (int c = 0; c < 4; c++)
#pragma unroll
      for (int r = 0; r < 4; r++)
        P[(wave * 16 + l4 * 4 + r) * 64 + c * 16 + l15] = f2bf(sacc[c][r]);
    __syncthreads();

#pragma unroll
    for (int u = 0; u < 2; u++) {
      if (u) __syncthreads();
#pragma unroll
      for (int t = 0; t < 4; t++) {
        int inst = wave * 4 + t;  // 32 insts, 16 V^T-rows x 32 cols
        gl_lds16(Vt + (size_t)(inst * 16 + (lane >> 2)) * 8192 + kb + u * 32 + (lane & 3) * 8,
                 &SH[inst * 512]);
      }
      __syncthreads();
      short8 a = *(const short8*)&P[(wave * 16 + l15) * 64 + u * 32 + l4 * 8];
#pragma unroll
      for (int f = 0; f < 32; f++) {
        short8 b = *(const short8*)&SH[(f * 16 + l15) * 32 + l4 * 8];
        o[f] = __builtin_amdgcn_mfma_f32_16x16x32_bf16(a, b, o[f], 0, 0, 0);
      }
    }
  }

#pragma unroll
  for (int r = 0; r < 4; r++) {
    int row = qb + wave * 16 + l4 * 4 + r;
    if (l15 == 0) {
      mpart[split * 8192 + row] = mi[r];
      lpart[split * 8192 + row] = li[r];
    }
  }
#pragma unroll
  for (int f = 0; f < 32; f++) {
    int col = f * 16 + l15;
#pragma unroll
    for (int r = 0; r < 4; r++) {
      int row = qb + wave * 16 + l4 * 4 + r;
      Opart[((size_t)split * 8192 + row) * 512 + col] = o[f][r];
    }
  }
}

// ---------- combine 4 split-K partials -> f32 out ----------
// Opart split stride = 8192*512 = 4194304 floats (round-1/2 bug: used 2x this).
__global__ void k_combine(const float* __restrict__ Opart, const float* __restrict__ mpart,
                          const float* __restrict__ lpart, float* __restrict__ out) {
  int gid = blockIdx.x * blockDim.x + threadIdx.x;  // 1,048,576 threads
  int row = gid >> 7;
  int c4 = (gid & 127) * 4;
  float m0 = mpart[row], m1 = mpart[8192 + row], m2 = mpart[16384 + row], m3 = mpart[24576 + row];
  float M = fmaxf(fmaxf(m0, m1), fmaxf(m2, m3));
  float w0 = __expf(m0 - M), w1 = __expf(m1 - M), w2 = __expf(m2 - M), w3 = __expf(m3 - M);
  float L = w0 * lpart[row] + w1 * lpart[8192 + row] +
            w2 * lpart[16384 + row] + w3 * lpart[24576 + row];
  const float* p = Opart + (size_t)row * 512 + c4;
  float4 a0 = *(const float4*)(p);
  float4 a1 = *(const float4*)(p + 4194304);
  float4 a2 = *(const float4*)(p + 8388608);
  float4 a3 = *(const float4*)(p + 12582912);
  float inv = 1.0f / L;
  float4 res;
  res.x = (w0 * a0.x + w1 * a1.x + w2 * a2.x + w3 * a3.x) * inv;
  res.y = (w0 * a0.y + w1 * a1.y + w2 * a2.y + w3 * a3.y) * inv;
  res.z = (w0 * a0.z + w1 * a1.z + w2 * a2.z + w3 * a3.z) * inv;
  res.w = (w0 * a0.w + w1 * a1.w + w2 * a2.w + w3 * a3.w) * inv;
  *(float4*)(out + (size_t)row * 512 + c4) = res;
}

extern "C" void kernel_launch(void* const* d_in, const int* in_sizes, int n_in,
                              void* d_out, int out_size, void* d_ws, size_t ws_size,
                              hipStream_t stream) {
  const void* Q   = d_in[0];
  const void* K   = d_in[1];
  const void* V   = d_in[2];
  const void* WQw = d_in[3];
  const void* WQb = d_in[4];
  const void* WKw = d_in[5];
  const void* WKb = d_in[6];
  const void* mask = d_in[7];
  float* out = (float*)d_out;
  char* ws = (char*)d_ws;
  (void)in_sizes; (void)n_in; (void)out_size; (void)ws_size;

  constexpr size_t SZ_MAT = (size_t)8192 * 512 * 2;  // 8 MB bf16
  size_t off = 4096;
  unsigned short* Qb  = (unsigned short*)(ws + off); off += SZ_MAT;
  unsigned short* Kb  = (unsigned short*)(ws + off); off += SZ_MAT;
  unsigned short* Wqb = (unsigned short*)(ws + off); off += (size_t)512 * 512 * 2;
  unsigned short* Wkb = (unsigned short*)(ws + off); off += (size_t)512 * 512 * 2;
  unsigned short* bqb = (unsigned short*)(ws + off); off += 1024;
  unsigned short* bkb = (unsigned short*)(ws + off); off += 1024;
  unsigned short* Vt  = (unsigned short*)(ws + off); off += SZ_MAT;
  unsigned short* Qp  = (unsigned short*)(ws + off); off += SZ_MAT;
  unsigned short* Kp  = (unsigned short*)(ws + off); off += SZ_MAT;
  unsigned long long* mbits = (unsigned long long*)(ws + off); off += (size_t)8192 * 128 * 8;
  float* Opart = (float*)(ws + off); off += (size_t)4 * 8192 * 512 * 4;
  float* mpart = (float*)(ws + off); off += (size_t)4 * 8192 * 4;
  float* lpart = (float*)(ws + off); off += (size_t)4 * 8192 * 4;
  int* fflag = (int*)ws;
  int* esize = (int*)(ws + 64);

  k_detect_f<<<1, 64, 0, stream>>>((const unsigned int*)Q, fflag);
  k_detect_m<<<1, 64, 0, stream>>>((const unsigned int*)mask, esize);
  k_cvt<<<2048, 256, 0, stream>>>(Q, Qb, fflag, 8192 * 512);
  k_cvt<<<2048, 256, 0, stream>>>(K, Kb, fflag, 8192 * 512);
  k_cvt<<<128, 256, 0, stream>>>(WQw, Wqb, fflag, 512 * 512);
  k_cvt<<<128, 256, 0, stream>>>(WKw, Wkb, fflag, 512 * 512);
  k_cvt<<<1, 64, 0, stream>>>(WQb, bqb, fflag, 512);
  k_cvt<<<1, 64, 0, stream>>>(WKb, bkb, fflag, 512);
  k_transpose_v<<<dim3(128, 8), 256, 0, stream>>>(V, fflag, Vt);
  k_pack<<<1024, 256, 0, stream>>>(mask, esize, mbits);
  k_proj<<<dim3(64, 4), 256, 0, stream>>>(Qb, Wqb, bqb, Qp);
  k_proj<<<dim3(64, 4), 256, 0, stream>>>(Kb, Wkb, bkb, Kp);
  k_attn<<<dim3(64, 4), 512, 0, stream>>>(Qp, Kp, Vt, mbits, Opart, mpart, lpart);
  k_combine<<<4096, 256, 0, stream>>>(Opart, mpart, lpart, out);
}